// Round 7
// baseline (77.469 us; speedup 1.0000x reference)
//
#include <hip/hip_runtime.h>
#include <stdint.h>

#define M_TOTAL 16384
#define N_TOTAL 1024
#define K_TOTAL 1024
#define BM 128
#define BN 128
#define BK 64
#define NTILES (K_TOTAL / BK)               // 16
#define NWG ((M_TOTAL / BM) * (N_TOTAL / BN)) // 1024

using f32x4  = __attribute__((ext_vector_type(4))) float;
using bf16x8 = __attribute__((ext_vector_type(8))) short;
using bf16x4 = __attribute__((ext_vector_type(4))) short;

#define AS1 __attribute__((address_space(1)))
#define AS3 __attribute__((address_space(3)))
#define SB() __builtin_amdgcn_sched_barrier(0)

__device__ __forceinline__ unsigned packrne(float x, float y) {
    unsigned ux = __builtin_bit_cast(unsigned, x);
    unsigned uy = __builtin_bit_cast(unsigned, y);
    ux += 0x7fffu + ((ux >> 16) & 1u);
    uy += 0x7fffu + ((uy >> 16) & 1u);
    return (ux >> 16) | (uy & 0xffff0000u);
}

// ---------------- kernel 1: W fp32 -> bf16 (tiny: 4 MB read, 2 MB write) ----
#define N8W (N_TOTAL * K_TOTAL / 8)   // 131072
__global__ __launch_bounds__(256) void cvtW_kernel(
    const float* __restrict__ W, uint4* __restrict__ Wb)
{
    const int i = blockIdx.x * 256 + threadIdx.x;
    const f32x4* p = (const f32x4*)W + (size_t)i * 2;
    const f32x4 a = p[0], b = p[1];
    uint4 r;
    r.x = packrne(a[0], a[1]);
    r.y = packrne(a[2], a[3]);
    r.z = packrne(b[0], b[1]);
    r.w = packrne(b[2], b[3]);
    Wb[i] = r;
}

// ---------------- kernel 2: fused fp32-X GEMM + bias ------------------------
// C[m][n] = sum_k X[m][k]*W[n][k] + bias[n].  X fp32 (converted in-register),
// W bf16 (ws).  128x128 tile, 4 waves (2x2, wave 64x64), BK=64, dbuf LDS 64KB
// -> 2 blocks/CU for cross-block overlap.  Per tile 2 phases (one per k-half):
// {stage B(t+1) gload_lds | issue A(t+1) f32 loads | ds_read frags |
//  convert+swizzled ds_write A(t+1) -> barrier -> lgkm0 -> 16 MFMA (setprio)
//  -> vmcnt(0) -> barrier}.
// LDS layout (A and B): row r (128B) holds k-group kg at 16B slot kg^(r&7).
__global__ __launch_bounds__(256) void gemm_fused_kernel(
    const float* __restrict__ X, const unsigned short* __restrict__ Wb,
    const float* __restrict__ bias, float* __restrict__ C)
{
    __shared__ __align__(16) char smem[65536];  // A: 2x16KB @0; B: 2x16KB @32768

    const int tid  = threadIdx.x;
    const int lane = tid & 63;
    const int wave = tid >> 6;      // 0..3
    const int wr = wave >> 1;       // 0..1 : 64-row strip
    const int wc = wave & 1;        // 0..1 : 64-col strip

    // XCD-chunked swizzle (verified r2-r6): one bm-panel's 8 bn-blocks
    // co-resident on one XCD -> X fp32 panel fetched from HBM ~once.
    const int bid  = blockIdx.x;
    const int work = (bid & 7) * (NWG / 8) + (bid >> 3);
    const int bm = work >> 3;
    const int bn = work & 7;
    const int m0 = bm * BM, n0 = bn * BN;

    // ---- B staging: gload_lds, linear dest + pre-swizzled source (r4-proven)
    const int kge = (((lane & 7) ^ ((lane >> 3) & 7)) << 3);
    auto stage_B = [&](int t, int b, int h) {
        #pragma unroll
        for (int j = 0; j < 2; ++j) {
            const int rb = h * 64 + wave * 16 + j * 8;     // B row (= col) base
            __builtin_amdgcn_global_load_lds(
                (const AS1 void*)(Wb + (size_t)(n0 + rb + (lane >> 3)) * K_TOTAL
                                     + t * BK + kge),
                (AS3 void*)(smem + 32768 + b * 16384 + rb * 128), 16, 0, 0);
        }
    };

    // ---- A staging: reg-load fp32, convert, swizzled ds_write --------------
    const int arow = tid >> 1;      // 0..127
    const int ac   = tid & 1;       // 16-float chunk within the 32-k half

    auto load_A = [&](int t, int ks, f32x4 (&v)[4]) {
        const float* p = X + (size_t)(m0 + arow) * K_TOTAL + t * BK + ks * 32 + ac * 16;
        v[0] = *(const f32x4*)(p);
        v[1] = *(const f32x4*)(p + 4);
        v[2] = *(const f32x4*)(p + 8);
        v[3] = *(const f32x4*)(p + 12);
    };
    auto write_A = [&](int b, int ks, const f32x4 (&v)[4]) {
        const int kg0 = ks * 4 + ac * 2;
        const int rs  = arow & 7;
        uint4 c0, c1;
        c0.x = packrne(v[0][0], v[0][1]); c0.y = packrne(v[0][2], v[0][3]);
        c0.z = packrne(v[1][0], v[1][1]); c0.w = packrne(v[1][2], v[1][3]);
        c1.x = packrne(v[2][0], v[2][1]); c1.y = packrne(v[2][2], v[2][3]);
        c1.z = packrne(v[3][0], v[3][1]); c1.w = packrne(v[3][2], v[3][3]);
        *(uint4*)(smem + b * 16384 + arow * 128 + (((kg0    ) ^ rs) << 4)) = c0;
        *(uint4*)(smem + b * 16384 + arow * 128 + (((kg0 + 1) ^ rs) << 4)) = c1;
    };

    // ---- fragment reads ----------------------------------------------------
    const int cl = lane & 15;
    const int kb = lane >> 4;       // 0..3
    const int sw = cl & 7;
    auto read_frags = [&](int b, int ks, bf16x8 (&aF)[4], bf16x8 (&bF)[4]) {
        const char* Ab = smem + b * 16384;
        const char* Bb = smem + 32768 + b * 16384;
        const int kg = ks * 4 + kb;
        #pragma unroll
        for (int i = 0; i < 4; ++i) {
            const int ar = wr * 64 + i * 16 + cl;
            aF[i] = *(const bf16x8*)(Ab + ar * 128 + ((kg ^ sw) << 4));
            const int br = wc * 64 + i * 16 + cl;
            bF[i] = *(const bf16x8*)(Bb + br * 128 + ((kg ^ sw) << 4));
        }
    };

    f32x4 acc[4][4] = {};

#define BARRIER() SB(); __builtin_amdgcn_s_barrier(); SB()
#define LGKM0()   asm volatile("s_waitcnt lgkmcnt(0)" ::: "memory"); SB()
#define VM0()     asm volatile("s_waitcnt vmcnt(0)" ::: "memory"); SB()

#define MFMA16(AF, BF)                                                          \
    __builtin_amdgcn_s_setprio(1);                                              \
    _Pragma("unroll")                                                           \
    for (int i = 0; i < 4; ++i) {                                               \
        _Pragma("unroll")                                                       \
        for (int j = 0; j < 4; ++j)                                             \
            acc[i][j] = __builtin_amdgcn_mfma_f32_16x16x32_bf16(                \
                AF[i], BF[j], acc[i][j], 0, 0, 0);                              \
    }                                                                           \
    __builtin_amdgcn_s_setprio(0);

    // ---- prologue: stage tile 0 completely --------------------------------
    {
        f32x4 a0[4], a1[4];
        stage_B(0, 0, 0);
        stage_B(0, 0, 1);
        load_A(0, 0, a0);
        load_A(0, 1, a1);
        write_A(0, 0, a0);
        write_A(0, 1, a1);
        LGKM0();    // my ds_writes visible
        VM0();      // my B gload_lds landed
        BARRIER();
    }

    // ---- main loop ---------------------------------------------------------
    #pragma unroll 1
    for (int t = 0; t < NTILES; ++t) {
        const int buf = t & 1, nbuf = buf ^ 1;
        const bool nx = (t + 1 < NTILES);
        bf16x8 aF0[4], bF0[4], aF1[4], bF1[4];
        f32x4 as0[4], as1[4];

        // ---- P0: k-half 0 ----
        if (nx) { stage_B(t + 1, nbuf, 0); load_A(t + 1, 0, as0); }
        read_frags(buf, 0, aF0, bF0);
        if (nx) write_A(nbuf, 0, as0);      // compiler vmcnt-wait lands here
        BARRIER();
        LGKM0();
        MFMA16(aF0, bF0);
        VM0();                              // B(t+1,h0) + A loads drained
        BARRIER();

        // ---- P1: k-half 1 ----
        if (nx) { stage_B(t + 1, nbuf, 1); load_A(t + 1, 1, as1); }
        read_frags(buf, 1, aF1, bF1);
        if (nx) write_A(nbuf, 1, as1);
        BARRIER();
        LGKM0();
        MFMA16(aF1, bF1);
        VM0();                              // B(t+1,h1) drained pre-consumption
        BARRIER();
    }

    // ---- epilogue: D element (row=(lane>>4)*4+r, col=lane&15) [m89] --------
    const int r0 = (lane >> 4) * 4;
    #pragma unroll
    for (int ni = 0; ni < 4; ++ni) {
        const int n = n0 + wc * 64 + ni * 16 + cl;
        const float bvv = bias[n];
        #pragma unroll
        for (int mi = 0; mi < 4; ++mi) {
            const int m = m0 + wr * 64 + mi * 16 + r0;
            #pragma unroll
            for (int r = 0; r < 4; ++r)
                C[(size_t)(m + r) * N_TOTAL + n] = acc[mi][ni][r] + bvv;
        }
    }
#undef MFMA16
#undef BARRIER
#undef LGKM0
#undef VM0
}

// ---------------- fallback: round-1 single kernel (known-good) --------------
__device__ __forceinline__ short f2bf(float f) {
    unsigned u = __builtin_bit_cast(unsigned, f);
    u += 0x7fffu + ((u >> 16) & 1u);
    return (short)(u >> 16);
}

__global__ __launch_bounds__(256) void fb_gemm_bias_kernel(
    const float* __restrict__ X, const float* __restrict__ W,
    const float* __restrict__ bias, float* __restrict__ C)
{
    __shared__ short As[BM * BK];
    __shared__ short Bs[BN * BK];

    const int tid  = threadIdx.x;
    const int lane = tid & 63;
    const int wave = tid >> 6;
    const int wr = wave >> 1;
    const int wc = wave & 1;

    const int bid  = blockIdx.x;
    const int work = (bid & 7) * (NWG / 8) + (bid >> 3);
    const int bm = work >> 3;
    const int bn = work & 7;
    const int m0 = bm * BM, n0 = bn * BN;

    const int srow  = tid >> 4;
    const int scol4 = tid & 15;

    f32x4 acc[4][4] = {};
    char* const Ab = (char*)As;
    char* const Bb = (char*)Bs;

    for (int k0 = 0; k0 < K_TOTAL; k0 += BK) {
        __syncthreads();
        #pragma unroll
        for (int pass = 0; pass < 8; ++pass) {
            const int row = srow + pass * 16;
            const int off = (row * (BK * 2) + scol4 * 8) ^ ((row & 7) << 4);
            {
                const f32x4 v = *(const f32x4*)(X + (size_t)(m0 + row) * K_TOTAL + k0 + scol4 * 4);
                bf16x4 b;
                b[0] = f2bf(v[0]); b[1] = f2bf(v[1]); b[2] = f2bf(v[2]); b[3] = f2bf(v[3]);
                *(bf16x4*)(Ab + off) = b;
            }
            {
                const f32x4 v = *(const f32x4*)(W + (size_t)(n0 + row) * K_TOTAL + k0 + scol4 * 4);
                bf16x4 b;
                b[0] = f2bf(v[0]); b[1] = f2bf(v[1]); b[2] = f2bf(v[2]); b[3] = f2bf(v[3]);
                *(bf16x4*)(Bb + off) = b;
            }
        }
        __syncthreads();

        #pragma unroll
        for (int ks = 0; ks < 2; ++ks) {
            const int kel = ks * 32 + ((lane >> 4) << 3);
            bf16x8 af[4], bfr[4];
            #pragma unroll
            for (int i = 0; i < 4; ++i) {
                const int arow = wr * 64 + i * 16 + (lane & 15);
                af[i]  = *(const bf16x8*)(Ab + ((arow * (BK * 2) + kel * 2) ^ ((arow & 7) << 4)));
                const int brow = wc * 64 + i * 16 + (lane & 15);
                bfr[i] = *(const bf16x8*)(Bb + ((brow * (BK * 2) + kel * 2) ^ ((brow & 7) << 4)));
            }
            #pragma unroll
            for (int mi = 0; mi < 4; ++mi)
                #pragma unroll
                for (int ni = 0; ni < 4; ++ni)
                    acc[mi][ni] = __builtin_amdgcn_mfma_f32_16x16x32_bf16(
                        af[mi], bfr[ni], acc[mi][ni], 0, 0, 0);
        }
    }

    const int cl = lane & 15;
    const int r0 = (lane >> 4) * 4;
    #pragma unroll
    for (int ni = 0; ni < 4; ++ni) {
        const int n = n0 + wc * 64 + ni * 16 + cl;
        const float bvv = bias[n];
        #pragma unroll
        for (int mi = 0; mi < 4; ++mi) {
            const int m = m0 + wr * 64 + mi * 16 + r0;
            #pragma unroll
            for (int r = 0; r < 4; ++r)
                C[(size_t)(m + r) * N_TOTAL + n] = acc[mi][ni][r] + bvv;
        }
    }
}

extern "C" void kernel_launch(void* const* d_in, const int* in_sizes, int n_in,
                              void* d_out, int out_size, void* d_ws, size_t ws_size,
                              hipStream_t stream) {
    // inputs: 0:X 1:Wq 2:bq 3:Wk 4:bk 5:Wv 6:bv
    // softmax rows sum to 1 => out = X @ Wv^T + bv exactly.
    const float* X  = (const float*)d_in[0];
    const float* Wv = (const float*)d_in[5];
    const float* bv = (const float*)d_in[6];
    float* out = (float*)d_out;

    const size_t WB_BYTES = (size_t)N_TOTAL * K_TOTAL * 2;   // 2 MiB

    if (ws_size >= WB_BYTES) {
        unsigned short* Wb = (unsigned short*)d_ws;
        cvtW_kernel<<<dim3(N8W / 256), dim3(256), 0, stream>>>(Wv, (uint4*)Wb);
        gemm_fused_kernel<<<dim3(NWG), dim3(256), 0, stream>>>(X, Wb, bv, out);
    } else {
        fb_gemm_bias_kernel<<<dim3(NWG), dim3(256), 0, stream>>>(X, Wv, bv, out);
    }
}

// Round 8
// 67.361 us; speedup vs baseline: 1.1501x; 1.1501x over previous
//
#include <hip/hip_runtime.h>
#include <stdint.h>

#define M_TOTAL 16384
#define N_TOTAL 1024
#define K_TOTAL 1024
#define BM 128
#define BN 128
#define BK 64
#define NTILES (K_TOTAL / BK)                 // 16
#define NWG ((M_TOTAL / BM) * (N_TOTAL / BN)) // 1024

using f32x4  = __attribute__((ext_vector_type(4))) float;
using bf16x8 = __attribute__((ext_vector_type(8))) short;
using bf16x4 = __attribute__((ext_vector_type(4))) short;

#define AS1 __attribute__((address_space(1)))
#define AS3 __attribute__((address_space(3)))
#define SB() __builtin_amdgcn_sched_barrier(0)

__device__ __forceinline__ unsigned packrne(float x, float y) {
    unsigned ux = __builtin_bit_cast(unsigned, x);
    unsigned uy = __builtin_bit_cast(unsigned, y);
    ux += 0x7fffu + ((ux >> 16) & 1u);
    uy += 0x7fffu + ((uy >> 16) & 1u);
    return (ux >> 16) | (uy & 0xffff0000u);
}

// ---------------- kernel 1: W fp32 -> bf16 (tiny: 4 MB read, 2 MB write) ----
#define N8W (N_TOTAL * K_TOTAL / 8)   // 131072
__global__ __launch_bounds__(256) void cvtW_kernel(
    const float* __restrict__ W, uint4* __restrict__ Wb)
{
    const int i = blockIdx.x * 256 + threadIdx.x;
    const f32x4* p = (const f32x4*)W + (size_t)i * 2;
    const f32x4 a = p[0], b = p[1];
    uint4 r;
    r.x = packrne(a[0], a[1]);
    r.y = packrne(a[2], a[3]);
    r.z = packrne(b[0], b[1]);
    r.w = packrne(b[2], b[3]);
    Wb[i] = r;
}

// ---------------- kernel 2: fused fp32-X GEMM + bias, depth-2 A pipeline ----
// C[m][n] = sum_k X[m][k]*W[n][k] + bias[n].  X fp32 converted in-register.
// 128x128 tile, 4 waves (2x2), BK=64, dbuf LDS 64KB -> 2 blocks/CU.
// Per tile (ONE barrier): {read h0 frags | stage_B(t+1) gload_lds x4 |
// issue load_A(t+2) x8 | MFMA h0 | read h1 frags | MFMA h1 |
// write_A(t+1) (compiler vmcnt(12) counted wait) | VM(8) (retire B(t+1),
// A(t+2) spans barrier) | LGKM0 | barrier}.
// LDS layout (A and B): row r (128B) holds k-group kg at 16B slot kg^(r&7).
__global__ __launch_bounds__(256, 2) void gemm_fused_kernel(
    const float* __restrict__ X, const unsigned short* __restrict__ Wb,
    const float* __restrict__ bias, float* __restrict__ C)
{
    __shared__ __align__(16) char smem[65536];  // A: 2x16KB @0; B: 2x16KB @32768

    const int tid  = threadIdx.x;
    const int lane = tid & 63;
    const int wave = tid >> 6;      // 0..3
    const int wr = wave >> 1;       // 0..1 : 64-row strip
    const int wc = wave & 1;        // 0..1 : 64-col strip

    // XCD-chunked swizzle (verified r2-r7): one bm-panel's 8 bn-blocks
    // co-resident on one XCD -> X fp32 panel fetched from HBM ~once.
    const int bid  = blockIdx.x;
    const int work = (bid & 7) * (NWG / 8) + (bid >> 3);
    const int bm = work >> 3;
    const int bn = work & 7;
    const int m0 = bm * BM, n0 = bn * BN;

    // ---- B staging: gload_lds, linear dest + pre-swizzled source (proven) --
    const int kge = (((lane & 7) ^ ((lane >> 3) & 7)) << 3);
    auto stage_B = [&](int t, int b, int h) {
        #pragma unroll
        for (int j = 0; j < 2; ++j) {
            const int rb = h * 64 + wave * 16 + j * 8;
            __builtin_amdgcn_global_load_lds(
                (const AS1 void*)(Wb + (size_t)(n0 + rb + (lane >> 3)) * K_TOTAL
                                     + t * BK + kge),
                (AS3 void*)(smem + 32768 + b * 16384 + rb * 128), 16, 0, 0);
        }
    };

    // ---- A staging: reg-load fp32 (issued 2 tiles early), convert, ds_write
    const int arow = tid >> 1;      // 0..127
    const int ac   = tid & 1;

    auto load_A = [&](int t, int ks, f32x4 (&v)[4]) {
        const float* p = X + (size_t)(m0 + arow) * K_TOTAL + t * BK + ks * 32 + ac * 16;
        v[0] = *(const f32x4*)(p);
        v[1] = *(const f32x4*)(p + 4);
        v[2] = *(const f32x4*)(p + 8);
        v[3] = *(const f32x4*)(p + 12);
    };
    auto write_A = [&](int b, int ks, const f32x4 (&v)[4]) {
        const int kg0 = ks * 4 + ac * 2;
        const int rs  = arow & 7;
        uint4 c0, c1;
        c0.x = packrne(v[0][0], v[0][1]); c0.y = packrne(v[0][2], v[0][3]);
        c0.z = packrne(v[1][0], v[1][1]); c0.w = packrne(v[1][2], v[1][3]);
        c1.x = packrne(v[2][0], v[2][1]); c1.y = packrne(v[2][2], v[2][3]);
        c1.z = packrne(v[3][0], v[3][1]); c1.w = packrne(v[3][2], v[3][3]);
        *(uint4*)(smem + b * 16384 + arow * 128 + (((kg0    ) ^ rs) << 4)) = c0;
        *(uint4*)(smem + b * 16384 + arow * 128 + (((kg0 + 1) ^ rs) << 4)) = c1;
    };

    // ---- fragment reads ----------------------------------------------------
    const int cl = lane & 15;
    const int kb = lane >> 4;
    const int sw = cl & 7;
    auto read_frags = [&](int b, int ks, bf16x8 (&aF)[4], bf16x8 (&bF)[4]) {
        const char* Ab = smem + b * 16384;
        const char* Bb = smem + 32768 + b * 16384;
        const int kg = ks * 4 + kb;
        #pragma unroll
        for (int i = 0; i < 4; ++i) {
            const int ar = wr * 64 + i * 16 + cl;
            aF[i] = *(const bf16x8*)(Ab + ar * 128 + ((kg ^ sw) << 4));
            const int br = wc * 64 + i * 16 + cl;
            bF[i] = *(const bf16x8*)(Bb + br * 128 + ((kg ^ sw) << 4));
        }
    };

    f32x4 acc[4][4] = {};

#define BARRIER() SB(); __builtin_amdgcn_s_barrier(); SB()
#define LGKM0()   asm volatile("s_waitcnt lgkmcnt(0)" ::: "memory"); SB()
#define VM(N)     asm volatile("s_waitcnt vmcnt(" #N ")" ::: "memory"); SB()

#define MFMA16(AF, BF)                                                          \
    __builtin_amdgcn_s_setprio(1);                                              \
    _Pragma("unroll")                                                           \
    for (int i = 0; i < 4; ++i) {                                               \
        _Pragma("unroll")                                                       \
        for (int j = 0; j < 4; ++j)                                             \
            acc[i][j] = __builtin_amdgcn_mfma_f32_16x16x32_bf16(                \
                AF[i], BF[j], acc[i][j], 0, 0, 0);                              \
    }                                                                           \
    __builtin_amdgcn_s_setprio(0);

    // Ping-pong A register sets (statically indexed -- rule #20):
    f32x4 aP0[4], aP1[4], aQ0[4], aQ1[4];

    // body(t): consume C0/C1 = A(t+1) regs; load A(t+2) into L0/L1.
#define TILE_BODY(T, C0, C1, L0, L1)                                            \
    {                                                                           \
        const int buf = (T) & 1, nbuf = buf ^ 1;                                \
        bf16x8 aF0[4], bF0[4], aF1[4], bF1[4];                                  \
        read_frags(buf, 0, aF0, bF0);                                           \
        if ((T) + 1 < NTILES) { stage_B((T) + 1, nbuf, 0);                      \
                                stage_B((T) + 1, nbuf, 1); }                    \
        if ((T) + 2 < NTILES) { load_A((T) + 2, 0, L0);                         \
                                load_A((T) + 2, 1, L1); }                       \
        MFMA16(aF0, bF0);                                                       \
        read_frags(buf, 1, aF1, bF1);                                           \
        MFMA16(aF1, bF1);                                                       \
        if ((T) + 1 < NTILES) {                                                 \
            write_A(nbuf, 0, C0);   /* compiler: counted vmcnt for A(T+1) */    \
            write_A(nbuf, 1, C1);                                               \
            if ((T) + 2 < NTILES) { VM(8); } else { VM(0); }                    \
            LGKM0();                                                            \
            BARRIER();                                                          \
        }                                                                       \
    }

    // ---- prologue: fill buf0 with tile 0; prefetch A(1) --------------------
    {
        load_A(0, 0, aQ0);          // oldest 8
        load_A(0, 1, aQ1);
        stage_B(0, 0, 0);           // +4 gload_lds
        stage_B(0, 0, 1);
        write_A(0, 0, aQ0);         // compiler: vmcnt(4) counted
        write_A(0, 1, aQ1);
        load_A(1, 0, aP0);          // A(1) -> consumed at end of tile 0
        load_A(1, 1, aP1);
        VM(8);                      // retire B(0) x4; A(1) x8 stay in flight
        LGKM0();
        BARRIER();
    }

    // ---- main loop: 2x unrolled for static reg ping-pong -------------------
    #pragma unroll 1
    for (int t = 0; t < NTILES; t += 2) {
        TILE_BODY(t,     aP0, aP1, aQ0, aQ1);   // consume A(t+1)=P, load A(t+2)->Q
        TILE_BODY(t + 1, aQ0, aQ1, aP0, aP1);   // consume A(t+2)=Q, load A(t+3)->P
    }

    // ---- epilogue: D element (row=(lane>>4)*4+r, col=lane&15) [m89] --------
    const int r0 = (lane >> 4) * 4;
    #pragma unroll
    for (int ni = 0; ni < 4; ++ni) {
        const int n = n0 + wc * 64 + ni * 16 + cl;
        const float bvv = bias[n];
        #pragma unroll
        for (int mi = 0; mi < 4; ++mi) {
            const int m = m0 + wr * 64 + mi * 16 + r0;
            #pragma unroll
            for (int r = 0; r < 4; ++r)
                C[(size_t)(m + r) * N_TOTAL + n] = acc[mi][ni][r] + bvv;
        }
    }
#undef TILE_BODY
#undef MFMA16
#undef BARRIER
#undef LGKM0
#undef VM
}

// ---------------- fallback: round-1 single kernel (known-good) --------------
__device__ __forceinline__ short f2bf(float f) {
    unsigned u = __builtin_bit_cast(unsigned, f);
    u += 0x7fffu + ((u >> 16) & 1u);
    return (short)(u >> 16);
}

__global__ __launch_bounds__(256) void fb_gemm_bias_kernel(
    const float* __restrict__ X, const float* __restrict__ W,
    const float* __restrict__ bias, float* __restrict__ C)
{
    __shared__ short As[BM * BK];
    __shared__ short Bs[BN * BK];

    const int tid  = threadIdx.x;
    const int lane = tid & 63;
    const int wave = tid >> 6;
    const int wr = wave >> 1;
    const int wc = wave & 1;

    const int bid  = blockIdx.x;
    const int work = (bid & 7) * (NWG / 8) + (bid >> 3);
    const int bm = work >> 3;
    const int bn = work & 7;
    const int m0 = bm * BM, n0 = bn * BN;

    const int srow  = tid >> 4;
    const int scol4 = tid & 15;

    f32x4 acc[4][4] = {};
    char* const Ab = (char*)As;
    char* const Bb = (char*)Bs;

    for (int k0 = 0; k0 < K_TOTAL; k0 += BK) {
        __syncthreads();
        #pragma unroll
        for (int pass = 0; pass < 8; ++pass) {
            const int row = srow + pass * 16;
            const int off = (row * (BK * 2) + scol4 * 8) ^ ((row & 7) << 4);
            {
                const f32x4 v = *(const f32x4*)(X + (size_t)(m0 + row) * K_TOTAL + k0 + scol4 * 4);
                bf16x4 b;
                b[0] = f2bf(v[0]); b[1] = f2bf(v[1]); b[2] = f2bf(v[2]); b[3] = f2bf(v[3]);
                *(bf16x4*)(Ab + off) = b;
            }
            {
                const f32x4 v = *(const f32x4*)(W + (size_t)(n0 + row) * K_TOTAL + k0 + scol4 * 4);
                bf16x4 b;
                b[0] = f2bf(v[0]); b[1] = f2bf(v[1]); b[2] = f2bf(v[2]); b[3] = f2bf(v[3]);
                *(bf16x4*)(Bb + off) = b;
            }
        }
        __syncthreads();

        #pragma unroll
        for (int ks = 0; ks < 2; ++ks) {
            const int kel = ks * 32 + ((lane >> 4) << 3);
            bf16x8 af[4], bfr[4];
            #pragma unroll
            for (int i = 0; i < 4; ++i) {
                const int arow = wr * 64 + i * 16 + (lane & 15);
                af[i]  = *(const bf16x8*)(Ab + ((arow * (BK * 2) + kel * 2) ^ ((arow & 7) << 4)));
                const int brow = wc * 64 + i * 16 + (lane & 15);
                bfr[i] = *(const bf16x8*)(Bb + ((brow * (BK * 2) + kel * 2) ^ ((brow & 7) << 4)));
            }
            #pragma unroll
            for (int mi = 0; mi < 4; ++mi)
                #pragma unroll
                for (int ni = 0; ni < 4; ++ni)
                    acc[mi][ni] = __builtin_amdgcn_mfma_f32_16x16x32_bf16(
                        af[mi], bfr[ni], acc[mi][ni], 0, 0, 0);
        }
    }

    const int cl = lane & 15;
    const int r0 = (lane >> 4) * 4;
    #pragma unroll
    for (int ni = 0; ni < 4; ++ni) {
        const int n = n0 + wc * 64 + ni * 16 + cl;
        const float bvv = bias[n];
        #pragma unroll
        for (int mi = 0; mi < 4; ++mi) {
            const int m = m0 + wr * 64 + mi * 16 + r0;
            #pragma unroll
            for (int r = 0; r < 4; ++r)
                C[(size_t)(m + r) * N_TOTAL + n] = acc[mi][ni][r] + bvv;
        }
    }
}

extern "C" void kernel_launch(void* const* d_in, const int* in_sizes, int n_in,
                              void* d_out, int out_size, void* d_ws, size_t ws_size,
                              hipStream_t stream) {
    // inputs: 0:X 1:Wq 2:bq 3:Wk 4:bk 5:Wv 6:bv
    // softmax rows sum to 1 => out = X @ Wv^T + bv exactly.
    const float* X  = (const float*)d_in[0];
    const float* Wv = (const float*)d_in[5];
    const float* bv = (const float*)d_in[6];
    float* out = (float*)d_out;

    const size_t WB_BYTES = (size_t)N_TOTAL * K_TOTAL * 2;   // 2 MiB

    if (ws_size >= WB_BYTES) {
        unsigned short* Wb = (unsigned short*)d_ws;
        cvtW_kernel<<<dim3(N8W / 256), dim3(256), 0, stream>>>(Wv, (uint4*)Wb);
        gemm_fused_kernel<<<dim3(NWG), dim3(256), 0, stream>>>(X, Wb, bv, out);
    } else {
        fb_gemm_bias_kernel<<<dim3(NWG), dim3(256), 0, stream>>>(X, Wv, bv, out);
    }
}